// Round 12
// baseline (525.985 us; speedup 1.0000x reference)
//
#include <hip/hip_runtime.h>
#include <hip/hip_bf16.h>

// GraphSage: 3x SAGEConv(mean) + linear head.
// Precision: packed split-bf16 (uint32 = hi<<16|lo, val = f(hi)+f(lo)).
// FUSED layer kernel: per 16-node tile — gather-mean into LDS (packed,
//   row stride 132 dwords: 2-way-only bank conflicts), then weight-stationary
//   MFMA (2 ct-tiles/wave, 256 thr — the r10 proven shape; r11's 1-ct/512thr
//   regressed: VGPR=64 -> B demoted from registers, FETCH +8MB, 65us).
//   Ping-pong hp buffers -> zero cross-block hazards, sbuf round-trip deleted.
//   NOTE: the grid-stride tile loop is load-bearing — it keeps the 128-VGPR
//   B-fragment set live across tiles (r6: 1 tile/block -> B re-read, 75us).
// CSR build: two-level MSD bucket sort — NO random global scatter (r7-r9:
//   atomic-cursor scatter is cross-XCD write-amplification bound, 57-175us).
// Aggregate part: 1 node/wave, uint2 lanes, 8-deep unroll — at the random
//   gather throughput ceiling (~3.7 TB/s; 8-deep == 16-deep).
// Head fused into layer 2. packed[] aliases hpB (consumed before L0 writes).

constexpr int NN = 50000;
constexpr int NE = 800000;
constexpr int NTILE = NN / 16;          // 3125 exact (NN = 16*3125)
constexpr int EPB = 4096;
constexpr int NBLK = (NE + EPB - 1) / EPB;   // 196
constexpr int NBUCK = 196;
constexpr int BCAP = 6144;
constexpr int LROW = 132;               // LDS row stride (dwords), 16B-aligned

using bf16x8 = __attribute__((ext_vector_type(8))) short;
using f32x4  = __attribute__((ext_vector_type(4))) float;

__device__ __forceinline__ unsigned short bf16_rne(float f) {
    unsigned u = __float_as_uint(f);
    unsigned r = (u + 0x7FFFu + ((u >> 16) & 1u)) >> 16;
    return (unsigned short)r;
}
__device__ __forceinline__ float bf16_f(unsigned short h) {
    return __uint_as_float(((unsigned)h) << 16);
}
__device__ __forceinline__ unsigned pack_split(float v) {
    unsigned short hi = bf16_rne(v);
    float r = v - bf16_f(hi);
    unsigned short lo = bf16_rne(r);
    return (((unsigned)hi) << 16) | (unsigned)lo;
}
__device__ __forceinline__ float unpack_f(unsigned p) {
    return __uint_as_float(p & 0xFFFF0000u) + __uint_as_float(p << 16);
}

// ---------------- CSR build (bucket sort) ----------------

__global__ __launch_bounds__(256) void k_hist(const int* __restrict__ ei,
                                              int* __restrict__ hist) {
    __shared__ int h[256];
    h[threadIdx.x] = 0;
    __syncthreads();
    int e0 = blockIdx.x * EPB;
    int e1 = e0 + EPB; if (e1 > NE) e1 = NE;
    for (int e = e0 + threadIdx.x; e < e1; e += 256)
        atomicAdd(&h[ei[NE + e] >> 8], 1);
    __syncthreads();
    hist[blockIdx.x * 256 + threadIdx.x] = h[threadIdx.x];
}

__global__ __launch_bounds__(256) void k_colscan(int* __restrict__ hist,
                                                 int* __restrict__ tot) {
    __shared__ int ws[4];
    int b = blockIdx.x;
    int t = threadIdx.x;
    int orig = (t < NBLK) ? hist[t * 256 + b] : 0;
    int v = orig;
    int lane = t & 63, wave = t >> 6;
    for (int o = 1; o < 64; o <<= 1) { int u = __shfl_up(v, o); if (lane >= o) v += u; }
    if (lane == 63) ws[wave] = v;
    __syncthreads();
    int off = 0;
    for (int w = 0; w < wave; ++w) off += ws[w];
    int st = v + off - orig;
    if (t < NBLK) hist[t * 256 + b] = st;
    if (t == 255) tot[b] = st + orig;
}

__global__ __launch_bounds__(256) void k_total(const int* __restrict__ tot,
                                               int* __restrict__ dbase) {
    __shared__ int ws[4];
    int t = threadIdx.x;
    int orig = tot[t];
    int v = orig;
    int lane = t & 63, wave = t >> 6;
    for (int o = 1; o < 64; o <<= 1) { int u = __shfl_up(v, o); if (lane >= o) v += u; }
    if (lane == 63) ws[wave] = v;
    __syncthreads();
    int off = 0;
    for (int w = 0; w < wave; ++w) off += ws[w];
    dbase[t] = v + off - orig;
    if (t == 255) dbase[256] = v + off;
}

__global__ __launch_bounds__(256) void k_addbase(int* __restrict__ hist,
                                                 const int* __restrict__ dbase) {
    hist[blockIdx.x * 256 + threadIdx.x] += dbase[threadIdx.x];
}

__global__ __launch_bounds__(256) void k_scatter1(const int* __restrict__ ei,
                                                  const int* __restrict__ hist,
                                                  unsigned* __restrict__ packed) {
    __shared__ int cur[256];
    cur[threadIdx.x] = hist[blockIdx.x * 256 + threadIdx.x];
    __syncthreads();
    int e0 = blockIdx.x * EPB;
    int e1 = e0 + EPB; if (e1 > NE) e1 = NE;
    for (int e = e0 + threadIdx.x; e < e1; e += 256) {
        int s = ei[e];
        int d = ei[NE + e];
        int pos = atomicAdd(&cur[d >> 8], 1);
        packed[pos] = ((unsigned)d << 16) | (unsigned)s;
    }
}

__global__ __launch_bounds__(256) void k_bucket_csr(const unsigned* __restrict__ packed,
        const int* __restrict__ dbase, unsigned short* __restrict__ perm,
        int* __restrict__ cnt, int* __restrict__ row_start) {
    __shared__ unsigned recs[BCAP];
    __shared__ unsigned short outs[BCAP];
    __shared__ int cntL[256];
    __shared__ int ws[4];
    int b = blockIdx.x;
    int lo = dbase[b];
    int m = dbase[b + 1] - lo;
    if (m > BCAP) m = BCAP;
    int t = threadIdx.x;
    cntL[t] = 0;
    __syncthreads();
    for (int i = t; i < m; i += 256) {
        unsigned r = packed[lo + i];
        recs[i] = r;
        atomicAdd(&cntL[(r >> 16) & 255], 1);
    }
    __syncthreads();
    int lane = t & 63, wave = t >> 6;
    int orig = cntL[t], v = orig;
    for (int o = 1; o < 64; o <<= 1) { int u = __shfl_up(v, o); if (lane >= o) v += u; }
    if (lane == 63) ws[wave] = v;
    __syncthreads();
    int off = 0;
    for (int w = 0; w < wave; ++w) off += ws[w];
    int st = v + off - orig;
    int node = b * 256 + t;
    if (node < NN) { cnt[node] = orig; row_start[node] = lo + st; }
    __syncthreads();
    cntL[t] = st;
    __syncthreads();
    for (int i = t; i < m; i += 256) {
        unsigned r = recs[i];
        int pos = atomicAdd(&cntL[(r >> 16) & 255], 1);
        outs[pos] = (unsigned short)(r & 0xFFFFu);
    }
    __syncthreads();
    for (int i = t; i < m; i += 256)
        perm[lo + i] = outs[i];
}

// ---------------- packing ----------------

__global__ void k_pack_x(const float* __restrict__ x, unsigned* __restrict__ xp) {
    int i = blockIdx.x * blockDim.x + threadIdx.x;
    constexpr int TOT = NN * 128 / 4;
    if (i < TOT) {
        float4 v = ((const float4*)x)[i];
        uint4 o;
        o.x = pack_split(v.x); o.y = pack_split(v.y);
        o.z = pack_split(v.z); o.w = pack_split(v.w);
        ((uint4*)xp)[i] = o;
    }
}

__global__ void k_pack_w(const float* __restrict__ Wl, const float* __restrict__ Wr,
                         unsigned short* __restrict__ whi, unsigned short* __restrict__ wlo) {
    int i = blockIdx.x * blockDim.x + threadIdx.x;
    if (i < 128 * 256) {
        int c = i >> 8;
        int k = i & 255;
        float v = (k < 128) ? Wl[c * 128 + k] : Wr[c * 128 + (k - 128)];
        unsigned short hi = bf16_rne(v);
        whi[i] = hi;
        wlo[i] = bf16_rne(v - bf16_f(hi));
    }
}

__global__ void k_init_out(float* __restrict__ out, const float* __restrict__ bf) {
    int i = blockIdx.x * blockDim.x + threadIdx.x;
    if (i < NN) out[i] = bf[0];
}

// ---------------- fused SAGE layer ----------------
// Per tile (16 nodes): phase A — each wave gathers/means 4 nodes from hp_in
// into LDS (packed split-bf16); phase B — MFMA with register-resident B,
// A0 from LDS, A1 (own rows) from hp_in; write hp_out. No cross-block hazard.
__global__ __launch_bounds__(256, 2) void k_sage_layer(
        const unsigned* __restrict__ hin, unsigned* __restrict__ hout,
        const int* __restrict__ row_start, const int* __restrict__ cnt,
        const unsigned short* __restrict__ perm,
        const unsigned short* __restrict__ Whi, const unsigned short* __restrict__ Wlo,
        const float* __restrict__ bias) {
    __shared__ unsigned lmean[16 * LROW];
    int wave = __builtin_amdgcn_readfirstlane(threadIdx.x >> 6);
    int lane = threadIdx.x & 63;
    int row = lane & 15;
    int kb = lane >> 4;
    int ct0 = wave * 2;

    bf16x8 bh[2][8], bl[2][8];
#pragma unroll
    for (int c = 0; c < 2; ++c)
#pragma unroll
        for (int kc = 0; kc < 8; ++kc) {
            size_t widx = (size_t)((ct0 + c) * 16 + row) * 256 + kc * 32 + kb * 8;
            bh[c][kc] = *(const bf16x8*)(Whi + widx);
            bl[c][kc] = *(const bf16x8*)(Wlo + widx);
        }
    float b0 = bias[ct0 * 16 + row];
    float b1 = bias[ct0 * 16 + 16 + row];

    const uint2* base = (const uint2*)hin;   // row stride = 64 uint2

    for (int t = blockIdx.x; t < NTILE; t += gridDim.x) {
        int n0 = t * 16;
        __syncthreads();   // previous tile's LDS reads complete
        // ---- phase A: gather-mean 4 nodes per wave ----
#pragma unroll
        for (int i = 0; i < 4; ++i) {
            int node = n0 + wave * 4 + i;
            int deg = cnt[node];
            int start = row_start[node];
            float ax = 0.f, ay = 0.f;
            int j = 0;
            for (; j + 8 <= deg; j += 8) {
                int s[8];
#pragma unroll
                for (int u = 0; u < 8; ++u) s[u] = perm[start + j + u];
                uint2 q[8];
#pragma unroll
                for (int u = 0; u < 8; ++u) q[u] = base[(size_t)s[u] * 64 + lane];
#pragma unroll
                for (int u = 0; u < 8; ++u) { ax += unpack_f(q[u].x); ay += unpack_f(q[u].y); }
            }
            for (; j < deg; ++j) {
                int s = perm[start + j];
                uint2 q = base[(size_t)s * 64 + lane];
                ax += unpack_f(q.x);
                ay += unpack_f(q.y);
            }
            float inv = 1.0f / (float)(deg > 1 ? deg : 1);
            lmean[(wave * 4 + i) * LROW + 2 * lane]     = pack_split(ax * inv);
            lmean[(wave * 4 + i) * LROW + 2 * lane + 1] = pack_split(ay * inv);
        }
        __syncthreads();
        // ---- phase B: MFMA ----
        const unsigned* a1 = hin + (size_t)(n0 + row) * 128 + kb * 8;
        f32x4 acc0 = {0.f, 0.f, 0.f, 0.f};
        f32x4 acc1 = {0.f, 0.f, 0.f, 0.f};
#pragma unroll
        for (int kc = 0; kc < 8; ++kc) {
            int kloc = (kc & 3) * 32 + kb * 8;
            const unsigned* ap = (kc < 4) ? &lmean[row * LROW + kloc] : (a1 + kloc - kb * 8);
            // for kc>=4: global addr = a1 + (kc&3)*32
            if (kc >= 4) ap = a1 + (kc & 3) * 32;
            uint4 q0 = *(const uint4*)ap;
            uint4 q1 = *(const uint4*)(ap + 4);
            unsigned pk[8] = {q0.x, q0.y, q0.z, q0.w, q1.x, q1.y, q1.z, q1.w};
            bf16x8 ah, al;
#pragma unroll
            for (int j = 0; j < 8; ++j) {
                ah[j] = (short)(pk[j] >> 16);
                al[j] = (short)(pk[j] & 0xFFFFu);
            }
            acc0 = __builtin_amdgcn_mfma_f32_16x16x32_bf16(ah, bh[0][kc], acc0, 0, 0, 0);
            acc0 = __builtin_amdgcn_mfma_f32_16x16x32_bf16(al, bh[0][kc], acc0, 0, 0, 0);
            acc0 = __builtin_amdgcn_mfma_f32_16x16x32_bf16(ah, bl[0][kc], acc0, 0, 0, 0);
            acc1 = __builtin_amdgcn_mfma_f32_16x16x32_bf16(ah, bh[1][kc], acc1, 0, 0, 0);
            acc1 = __builtin_amdgcn_mfma_f32_16x16x32_bf16(al, bh[1][kc], acc1, 0, 0, 0);
            acc1 = __builtin_amdgcn_mfma_f32_16x16x32_bf16(ah, bl[1][kc], acc1, 0, 0, 0);
        }
        int cb0 = ct0 * 16 + row;
#pragma unroll
        for (int r = 0; r < 4; ++r) {
            int n = n0 + kb * 4 + r;         // D: col=lane&15, row=(lane>>4)*4+reg
            unsigned* orow = hout + (size_t)n * 128;
            orow[cb0]      = pack_split(fmaxf(acc0[r] + b0, 0.f));
            orow[cb0 + 16] = pack_split(fmaxf(acc1[r] + b1, 0.f));
        }
    }
}

// layer-2 + head: out[n] += sum_c relu(h3[n][c]) * Wf[c]   (out preinit = bf)
__global__ __launch_bounds__(256, 2) void k_sage_layer_head(
        const unsigned* __restrict__ hin,
        const int* __restrict__ row_start, const int* __restrict__ cnt,
        const unsigned short* __restrict__ perm,
        const unsigned short* __restrict__ Whi, const unsigned short* __restrict__ Wlo,
        const float* __restrict__ bias, const float* __restrict__ Wf,
        float* __restrict__ out) {
    __shared__ unsigned lmean[16 * LROW];
    int wave = __builtin_amdgcn_readfirstlane(threadIdx.x >> 6);
    int lane = threadIdx.x & 63;
    int row = lane & 15;
    int kb = lane >> 4;
    int ct0 = wave * 2;

    bf16x8 bh[2][8], bl[2][8];
#pragma unroll
    for (int c = 0; c < 2; ++c)
#pragma unroll
        for (int kc = 0; kc < 8; ++kc) {
            size_t widx = (size_t)((ct0 + c) * 16 + row) * 256 + kc * 32 + kb * 8;
            bh[c][kc] = *(const bf16x8*)(Whi + widx);
            bl[c][kc] = *(const bf16x8*)(Wlo + widx);
        }
    float b0 = bias[ct0 * 16 + row];
    float b1 = bias[ct0 * 16 + 16 + row];
    float w0 = Wf[ct0 * 16 + row];
    float w1 = Wf[ct0 * 16 + 16 + row];

    const uint2* base = (const uint2*)hin;

    for (int t = blockIdx.x; t < NTILE; t += gridDim.x) {
        int n0 = t * 16;
        __syncthreads();
#pragma unroll
        for (int i = 0; i < 4; ++i) {
            int node = n0 + wave * 4 + i;
            int deg = cnt[node];
            int start = row_start[node];
            float ax = 0.f, ay = 0.f;
            int j = 0;
            for (; j + 8 <= deg; j += 8) {
                int s[8];
#pragma unroll
                for (int u = 0; u < 8; ++u) s[u] = perm[start + j + u];
                uint2 q[8];
#pragma unroll
                for (int u = 0; u < 8; ++u) q[u] = base[(size_t)s[u] * 64 + lane];
#pragma unroll
                for (int u = 0; u < 8; ++u) { ax += unpack_f(q[u].x); ay += unpack_f(q[u].y); }
            }
            for (; j < deg; ++j) {
                int s = perm[start + j];
                uint2 q = base[(size_t)s * 64 + lane];
                ax += unpack_f(q.x);
                ay += unpack_f(q.y);
            }
            float inv = 1.0f / (float)(deg > 1 ? deg : 1);
            lmean[(wave * 4 + i) * LROW + 2 * lane]     = pack_split(ax * inv);
            lmean[(wave * 4 + i) * LROW + 2 * lane + 1] = pack_split(ay * inv);
        }
        __syncthreads();
        const unsigned* a1 = hin + (size_t)(n0 + row) * 128 + kb * 8;
        f32x4 acc0 = {0.f, 0.f, 0.f, 0.f};
        f32x4 acc1 = {0.f, 0.f, 0.f, 0.f};
#pragma unroll
        for (int kc = 0; kc < 8; ++kc) {
            int kloc = (kc & 3) * 32 + kb * 8;
            const unsigned* ap = (kc < 4) ? &lmean[row * LROW + kloc]
                                          : (a1 + (kc & 3) * 32);
            uint4 q0 = *(const uint4*)ap;
            uint4 q1 = *(const uint4*)(ap + 4);
            unsigned pk[8] = {q0.x, q0.y, q0.z, q0.w, q1.x, q1.y, q1.z, q1.w};
            bf16x8 ah, al;
#pragma unroll
            for (int j = 0; j < 8; ++j) {
                ah[j] = (short)(pk[j] >> 16);
                al[j] = (short)(pk[j] & 0xFFFFu);
            }
            acc0 = __builtin_amdgcn_mfma_f32_16x16x32_bf16(ah, bh[0][kc], acc0, 0, 0, 0);
            acc0 = __builtin_amdgcn_mfma_f32_16x16x32_bf16(al, bh[0][kc], acc0, 0, 0, 0);
            acc0 = __builtin_amdgcn_mfma_f32_16x16x32_bf16(ah, bl[0][kc], acc0, 0, 0, 0);
            acc1 = __builtin_amdgcn_mfma_f32_16x16x32_bf16(ah, bh[1][kc], acc1, 0, 0, 0);
            acc1 = __builtin_amdgcn_mfma_f32_16x16x32_bf16(al, bh[1][kc], acc1, 0, 0, 0);
            acc1 = __builtin_amdgcn_mfma_f32_16x16x32_bf16(ah, bl[1][kc], acc1, 0, 0, 0);
        }
        float part[4];
#pragma unroll
        for (int r = 0; r < 4; ++r)
            part[r] = fmaxf(acc0[r] + b0, 0.f) * w0 + fmaxf(acc1[r] + b1, 0.f) * w1;
#pragma unroll
        for (int o = 1; o < 16; o <<= 1) {
#pragma unroll
            for (int r = 0; r < 4; ++r) part[r] += __shfl_xor(part[r], o);
        }
        if (row == 0) {
#pragma unroll
            for (int r = 0; r < 4; ++r) atomicAdd(&out[n0 + kb * 4 + r], part[r]);
        }
    }
}

extern "C" void kernel_launch(void* const* d_in, const int* in_sizes, int n_in,
                              void* d_out, int out_size, void* d_ws, size_t ws_size,
                              hipStream_t stream) {
    const float* x   = (const float*)d_in[0];
    const int*   ei  = (const int*)d_in[1];
    const float* Wl0 = (const float*)d_in[2];
    const float* bl0 = (const float*)d_in[3];
    const float* Wr0 = (const float*)d_in[4];
    const float* Wl1 = (const float*)d_in[5];
    const float* bl1 = (const float*)d_in[6];
    const float* Wr1 = (const float*)d_in[7];
    const float* Wl2 = (const float*)d_in[8];
    const float* bl2 = (const float*)d_in[9];
    const float* Wr2 = (const float*)d_in[10];
    const float* Wf  = (const float*)d_in[11];
    const float* bf  = (const float*)d_in[12];
    float* out = (float*)d_out;

    char* p = (char*)d_ws;
    auto alloc = [&](size_t n) { void* r = (void*)p; p += (n + 255) & ~(size_t)255; return r; };
    int*            hist      = (int*)alloc((size_t)NBLK * 256 * 4);
    int*            tot       = (int*)alloc(256 * 4);
    int*            dbase     = (int*)alloc(257 * 4);
    int*            cnt       = (int*)alloc((size_t)NN * 4);
    int*            row_start = (int*)alloc((size_t)NN * 4);
    unsigned short* perm      = (unsigned short*)alloc((size_t)NE * 2);
    unsigned*       hpA       = (unsigned*)alloc((size_t)NN * 128 * 4);
    unsigned*       hpB       = (unsigned*)alloc((size_t)NN * 128 * 4);
    unsigned short* whi       = (unsigned short*)alloc((size_t)3 * 128 * 256 * 2);
    unsigned short* wlo       = (unsigned short*)alloc((size_t)3 * 128 * 256 * 2);
    unsigned*       packed    = hpB;   // alias: consumed (bucket_csr) before L0 writes hpB

    dim3 b256(256);
    // CSR build via bucket sort
    k_hist<<<dim3(NBLK), b256, 0, stream>>>(ei, hist);
    k_colscan<<<dim3(256), b256, 0, stream>>>(hist, tot);
    k_total<<<dim3(1), b256, 0, stream>>>(tot, dbase);
    k_addbase<<<dim3(NBLK), b256, 0, stream>>>(hist, dbase);
    k_scatter1<<<dim3(NBLK), b256, 0, stream>>>(ei, hist, packed);
    k_bucket_csr<<<dim3(NBUCK), b256, 0, stream>>>(packed, dbase, perm, cnt, row_start);

    // packing + out init
    k_pack_x<<<dim3((NN * 128 / 4 + 255) / 256), b256, 0, stream>>>(x, hpA);
    k_pack_w<<<dim3(128), b256, 0, stream>>>(Wl0, Wr0, whi + 0 * 32768, wlo + 0 * 32768);
    k_pack_w<<<dim3(128), b256, 0, stream>>>(Wl1, Wr1, whi + 1 * 32768, wlo + 1 * 32768);
    k_pack_w<<<dim3(128), b256, 0, stream>>>(Wl2, Wr2, whi + 2 * 32768, wlo + 2 * 32768);
    k_init_out<<<dim3((NN + 255) / 256), b256, 0, stream>>>(out, bf);

    dim3 gL(512);   // 2 blocks/CU; grid-stride over 3125 tiles

    // layer 0: hpA -> hpB
    k_sage_layer<<<gL, b256, 0, stream>>>(hpA, hpB, row_start, cnt, perm,
                                          whi + 0 * 32768, wlo + 0 * 32768, bl0);
    // layer 1: hpB -> hpA
    k_sage_layer<<<gL, b256, 0, stream>>>(hpB, hpA, row_start, cnt, perm,
                                          whi + 1 * 32768, wlo + 1 * 32768, bl1);
    // layer 2 + head: hpA -> out
    k_sage_layer_head<<<gL, b256, 0, stream>>>(hpA, row_start, cnt, perm,
                                               whi + 2 * 32768, wlo + 2 * 32768,
                                               bl2, Wf, out);
}

// Round 13
// 399.555 us; speedup vs baseline: 1.3164x; 1.3164x over previous
//
#include <hip/hip_runtime.h>
#include <hip/hip_bf16.h>

// GraphSage: 3x SAGEConv(mean) + linear head.
// Precision: packed split-bf16 (uint32 = hi<<16|lo, val = f(hi)+f(lo)).
// Structure = round-10 champion (414us): SEPARATE aggregate and GEMM.
//   r12 fusion regressed (135us/layer): gather needs ~50k concurrent waves;
//   fused-behind-barrier starves it (19% occ, no gather/MFMA overlap).
// GEMM: weight-stationary MFMA, 2 ct-tiles/wave, 256 thr, GRID-STRIDE loop.
//   NOTE: grid-stride loop is load-bearing — keeps the 128-VGPR B set live
//   (r6: 1 tile/block -> B demoted, 75us; r11: 1-ct/512thr -> VGPR=64,
//   B demoted, 65us). NEW r13: all 16 A dwordx4 loads issued UP FRONT per
//   tile (64 VGPRs) -> 8x memory parallelism for the streaming A read
//   (GEMM was at 700 GB/s on a 77MB/layer stream = MLP-bound).
// CSR build: two-level MSD bucket sort — NO random global scatter (r7-r9:
//   atomic-cursor scatter is cross-XCD write-amplification bound, 57-175us).
//   Parallel basescan (r11): colscan + total + addbase.
// Aggregate: 1 node/wave, uint2 lanes, 16-deep unroll — at the random-gather
//   throughput ceiling (~3.7 TB/s; 8-deep == 16-deep == 2-nodes/wave == 55us).
// Head fused into layer-2 GEMM. packed[] aliases sbuf (disjoint lifetime).

constexpr int NN = 50000;
constexpr int NE = 800000;
constexpr int NTILE = NN / 16;          // 3125 exact
constexpr int EPB = 4096;
constexpr int NBLK = (NE + EPB - 1) / EPB;   // 196
constexpr int NBUCK = 196;
constexpr int BCAP = 6144;

using bf16x8 = __attribute__((ext_vector_type(8))) short;
using f32x4  = __attribute__((ext_vector_type(4))) float;

__device__ __forceinline__ unsigned short bf16_rne(float f) {
    unsigned u = __float_as_uint(f);
    unsigned r = (u + 0x7FFFu + ((u >> 16) & 1u)) >> 16;
    return (unsigned short)r;
}
__device__ __forceinline__ float bf16_f(unsigned short h) {
    return __uint_as_float(((unsigned)h) << 16);
}
__device__ __forceinline__ unsigned pack_split(float v) {
    unsigned short hi = bf16_rne(v);
    float r = v - bf16_f(hi);
    unsigned short lo = bf16_rne(r);
    return (((unsigned)hi) << 16) | (unsigned)lo;
}
__device__ __forceinline__ float unpack_f(unsigned p) {
    return __uint_as_float(p & 0xFFFF0000u) + __uint_as_float(p << 16);
}

// ---------------- CSR build (bucket sort) ----------------

__global__ __launch_bounds__(256) void k_hist(const int* __restrict__ ei,
                                              int* __restrict__ hist) {
    __shared__ int h[256];
    h[threadIdx.x] = 0;
    __syncthreads();
    int e0 = blockIdx.x * EPB;
    int e1 = e0 + EPB; if (e1 > NE) e1 = NE;
    for (int e = e0 + threadIdx.x; e < e1; e += 256)
        atomicAdd(&h[ei[NE + e] >> 8], 1);
    __syncthreads();
    hist[blockIdx.x * 256 + threadIdx.x] = h[threadIdx.x];
}

__global__ __launch_bounds__(256) void k_colscan(int* __restrict__ hist,
                                                 int* __restrict__ tot) {
    __shared__ int ws[4];
    int b = blockIdx.x;
    int t = threadIdx.x;
    int orig = (t < NBLK) ? hist[t * 256 + b] : 0;
    int v = orig;
    int lane = t & 63, wave = t >> 6;
    for (int o = 1; o < 64; o <<= 1) { int u = __shfl_up(v, o); if (lane >= o) v += u; }
    if (lane == 63) ws[wave] = v;
    __syncthreads();
    int off = 0;
    for (int w = 0; w < wave; ++w) off += ws[w];
    int st = v + off - orig;
    if (t < NBLK) hist[t * 256 + b] = st;
    if (t == 255) tot[b] = st + orig;
}

__global__ __launch_bounds__(256) void k_total(const int* __restrict__ tot,
                                               int* __restrict__ dbase) {
    __shared__ int ws[4];
    int t = threadIdx.x;
    int orig = tot[t];
    int v = orig;
    int lane = t & 63, wave = t >> 6;
    for (int o = 1; o < 64; o <<= 1) { int u = __shfl_up(v, o); if (lane >= o) v += u; }
    if (lane == 63) ws[wave] = v;
    __syncthreads();
    int off = 0;
    for (int w = 0; w < wave; ++w) off += ws[w];
    dbase[t] = v + off - orig;
    if (t == 255) dbase[256] = v + off;
}

__global__ __launch_bounds__(256) void k_addbase(int* __restrict__ hist,
                                                 const int* __restrict__ dbase) {
    hist[blockIdx.x * 256 + threadIdx.x] += dbase[threadIdx.x];
}

__global__ __launch_bounds__(256) void k_scatter1(const int* __restrict__ ei,
                                                  const int* __restrict__ hist,
                                                  unsigned* __restrict__ packed) {
    __shared__ int cur[256];
    cur[threadIdx.x] = hist[blockIdx.x * 256 + threadIdx.x];
    __syncthreads();
    int e0 = blockIdx.x * EPB;
    int e1 = e0 + EPB; if (e1 > NE) e1 = NE;
    for (int e = e0 + threadIdx.x; e < e1; e += 256) {
        int s = ei[e];
        int d = ei[NE + e];
        int pos = atomicAdd(&cur[d >> 8], 1);
        packed[pos] = ((unsigned)d << 16) | (unsigned)s;
    }
}

__global__ __launch_bounds__(256) void k_bucket_csr(const unsigned* __restrict__ packed,
        const int* __restrict__ dbase, unsigned short* __restrict__ perm,
        int* __restrict__ cnt, int* __restrict__ row_start) {
    __shared__ unsigned recs[BCAP];
    __shared__ unsigned short outs[BCAP];
    __shared__ int cntL[256];
    __shared__ int ws[4];
    int b = blockIdx.x;
    int lo = dbase[b];
    int m = dbase[b + 1] - lo;
    if (m > BCAP) m = BCAP;
    int t = threadIdx.x;
    cntL[t] = 0;
    __syncthreads();
    for (int i = t; i < m; i += 256) {
        unsigned r = packed[lo + i];
        recs[i] = r;
        atomicAdd(&cntL[(r >> 16) & 255], 1);
    }
    __syncthreads();
    int lane = t & 63, wave = t >> 6;
    int orig = cntL[t], v = orig;
    for (int o = 1; o < 64; o <<= 1) { int u = __shfl_up(v, o); if (lane >= o) v += u; }
    if (lane == 63) ws[wave] = v;
    __syncthreads();
    int off = 0;
    for (int w = 0; w < wave; ++w) off += ws[w];
    int st = v + off - orig;
    int node = b * 256 + t;
    if (node < NN) { cnt[node] = orig; row_start[node] = lo + st; }
    __syncthreads();
    cntL[t] = st;
    __syncthreads();
    for (int i = t; i < m; i += 256) {
        unsigned r = recs[i];
        int pos = atomicAdd(&cntL[(r >> 16) & 255], 1);
        outs[pos] = (unsigned short)(r & 0xFFFFu);
    }
    __syncthreads();
    for (int i = t; i < m; i += 256)
        perm[lo + i] = outs[i];
}

// ---------------- packing ----------------

__global__ void k_pack_x(const float* __restrict__ x, unsigned* __restrict__ xp) {
    int i = blockIdx.x * blockDim.x + threadIdx.x;
    constexpr int TOT = NN * 128 / 4;
    if (i < TOT) {
        float4 v = ((const float4*)x)[i];
        uint4 o;
        o.x = pack_split(v.x); o.y = pack_split(v.y);
        o.z = pack_split(v.z); o.w = pack_split(v.w);
        ((uint4*)xp)[i] = o;
    }
}

__global__ void k_pack_w(const float* __restrict__ Wl, const float* __restrict__ Wr,
                         unsigned short* __restrict__ whi, unsigned short* __restrict__ wlo) {
    int i = blockIdx.x * blockDim.x + threadIdx.x;
    if (i < 128 * 256) {
        int c = i >> 8;
        int k = i & 255;
        float v = (k < 128) ? Wl[c * 128 + k] : Wr[c * 128 + (k - 128)];
        unsigned short hi = bf16_rne(v);
        whi[i] = hi;
        wlo[i] = bf16_rne(v - bf16_f(hi));
    }
}

__global__ void k_init_out(float* __restrict__ out, const float* __restrict__ bf) {
    int i = blockIdx.x * blockDim.x + threadIdx.x;
    if (i < NN) out[i] = bf[0];
}

// ---------------- aggregate (mean over CSR neighbors) ----------------
// one wave per node; lane l holds cols [2l, 2l+1] (packed uint2).
__global__ __launch_bounds__(256) void k_aggregate(const unsigned* __restrict__ hp,
        const int* __restrict__ row_start, const int* __restrict__ cnt,
        const unsigned short* __restrict__ perm, unsigned* __restrict__ outp) {
    int wave = __builtin_amdgcn_readfirstlane(threadIdx.x >> 6);
    int lane = threadIdx.x & 63;
    int node = blockIdx.x * 4 + wave;
    if (node >= NN) return;
    int deg = cnt[node];
    int start = row_start[node];
    const uint2* base = (const uint2*)hp;    // row stride = 64 uint2
    float ax = 0.f, ay = 0.f;
    int j = 0;
    for (; j + 16 <= deg; j += 16) {
        int s[16];
#pragma unroll
        for (int u = 0; u < 16; ++u) s[u] = perm[start + j + u];
        uint2 q[16];
#pragma unroll
        for (int u = 0; u < 16; ++u) q[u] = base[(size_t)s[u] * 64 + lane];
#pragma unroll
        for (int u = 0; u < 16; ++u) { ax += unpack_f(q[u].x); ay += unpack_f(q[u].y); }
    }
    for (; j + 4 <= deg; j += 4) {
        int s[4];
#pragma unroll
        for (int u = 0; u < 4; ++u) s[u] = perm[start + j + u];
        uint2 q[4];
#pragma unroll
        for (int u = 0; u < 4; ++u) q[u] = base[(size_t)s[u] * 64 + lane];
#pragma unroll
        for (int u = 0; u < 4; ++u) { ax += unpack_f(q[u].x); ay += unpack_f(q[u].y); }
    }
    for (; j < deg; ++j) {
        int s = perm[start + j];
        uint2 q = base[(size_t)s * 64 + lane];
        ax += unpack_f(q.x);
        ay += unpack_f(q.y);
    }
    float inv = 1.0f / (float)(deg > 1 ? deg : 1);
    uint2 o;
    o.x = pack_split(ax * inv);
    o.y = pack_split(ay * inv);
    ((uint2*)(outp + (size_t)node * 128))[lane] = o;
}

// ---------------- weight-stationary MFMA GEMM (grid-stride) ----------------
// out[n][c] = relu( bias[c] + sum_k [A0|A1][n][k] W[c][k] )
// Wave w owns cols [32w,32w+32): B hi/lo = 128 VGPRs, live across tiles.
// Per tile: ALL 16 A dwordx4 loads issued up front (64 VGPRs) -> high MLP.
// One block per tile range; __syncthreads() between tile reads and writes.
__global__ __launch_bounds__(256, 2) void k_gemm_ws(
        const unsigned* __restrict__ A0p, const unsigned* __restrict__ A1p,
        const unsigned short* __restrict__ Whi, const unsigned short* __restrict__ Wlo,
        const float* __restrict__ bias, unsigned* __restrict__ outp) {
    int wave = __builtin_amdgcn_readfirstlane(threadIdx.x >> 6);
    int lane = threadIdx.x & 63;
    int row = lane & 15;
    int kb = lane >> 4;
    int ct0 = wave * 2;

    bf16x8 bh[2][8], bl[2][8];
#pragma unroll
    for (int c = 0; c < 2; ++c)
#pragma unroll
        for (int kc = 0; kc < 8; ++kc) {
            size_t widx = (size_t)((ct0 + c) * 16 + row) * 256 + kc * 32 + kb * 8;
            bh[c][kc] = *(const bf16x8*)(Whi + widx);
            bl[c][kc] = *(const bf16x8*)(Wlo + widx);
        }
    float b0 = bias[ct0 * 16 + row];
    float b1 = bias[ct0 * 16 + 16 + row];

    for (int t = blockIdx.x; t < NTILE; t += gridDim.x) {
        int n0 = t * 16;
        const unsigned* a0 = A0p + (size_t)(n0 + row) * 128 + kb * 8;
        const unsigned* a1 = A1p + (size_t)(n0 + row) * 128 + kb * 8;
        // issue all 16 independent A loads before any MFMA
        uint4 aq[16];
#pragma unroll
        for (int kc = 0; kc < 4; ++kc) {
            aq[2 * kc + 0] = *(const uint4*)(a0 + kc * 32);
            aq[2 * kc + 1] = *(const uint4*)(a0 + kc * 32 + 4);
        }
#pragma unroll
        for (int kc = 0; kc < 4; ++kc) {
            aq[8 + 2 * kc + 0] = *(const uint4*)(a1 + kc * 32);
            aq[8 + 2 * kc + 1] = *(const uint4*)(a1 + kc * 32 + 4);
        }
        f32x4 acc0 = {0.f, 0.f, 0.f, 0.f};
        f32x4 acc1 = {0.f, 0.f, 0.f, 0.f};
#pragma unroll
        for (int kc = 0; kc < 8; ++kc) {
            uint4 q0 = aq[2 * kc];
            uint4 q1 = aq[2 * kc + 1];
            unsigned pk[8] = {q0.x, q0.y, q0.z, q0.w, q1.x, q1.y, q1.z, q1.w};
            bf16x8 ah, al;
#pragma unroll
            for (int j = 0; j < 8; ++j) {
                ah[j] = (short)(pk[j] >> 16);
                al[j] = (short)(pk[j] & 0xFFFFu);
            }
            acc0 = __builtin_amdgcn_mfma_f32_16x16x32_bf16(ah, bh[0][kc], acc0, 0, 0, 0);
            acc0 = __builtin_amdgcn_mfma_f32_16x16x32_bf16(al, bh[0][kc], acc0, 0, 0, 0);
            acc0 = __builtin_amdgcn_mfma_f32_16x16x32_bf16(ah, bl[0][kc], acc0, 0, 0, 0);
            acc1 = __builtin_amdgcn_mfma_f32_16x16x32_bf16(ah, bh[1][kc], acc1, 0, 0, 0);
            acc1 = __builtin_amdgcn_mfma_f32_16x16x32_bf16(al, bh[1][kc], acc1, 0, 0, 0);
            acc1 = __builtin_amdgcn_mfma_f32_16x16x32_bf16(ah, bl[1][kc], acc1, 0, 0, 0);
        }
        __syncthreads();   // all waves' reads of this tile's rows precede writes
        int cb0 = ct0 * 16 + row;
#pragma unroll
        for (int r = 0; r < 4; ++r) {
            int n = n0 + kb * 4 + r;         // D: col=lane&15, row=(lane>>4)*4+reg
            unsigned* orow = outp + (size_t)n * 128;
            orow[cb0]      = pack_split(fmaxf(acc0[r] + b0, 0.f));
            orow[cb0 + 16] = pack_split(fmaxf(acc1[r] + b1, 0.f));
        }
    }
}

// layer-2 variant: head fused — out[n] += sum_c relu(h3[n][c]) * Wf[c]
__global__ __launch_bounds__(256, 2) void k_gemm_head(
        const unsigned* __restrict__ A0p, const unsigned* __restrict__ A1p,
        const unsigned short* __restrict__ Whi, const unsigned short* __restrict__ Wlo,
        const float* __restrict__ bias, const float* __restrict__ Wf,
        float* __restrict__ out) {
    int wave = __builtin_amdgcn_readfirstlane(threadIdx.x >> 6);
    int lane = threadIdx.x & 63;
    int row = lane & 15;
    int kb = lane >> 4;
    int ct0 = wave * 2;

    bf16x8 bh[2][8], bl[2][8];
#pragma unroll
    for (int c = 0; c < 2; ++c)
#pragma unroll
        for (int kc = 0; kc < 8; ++kc) {
            size_t widx = (size_t)((ct0 + c) * 16 + row) * 256 + kc * 32 + kb * 8;
            bh[c][kc] = *(const bf16x8*)(Whi + widx);
            bl[c][kc] = *(const bf16x8*)(Wlo + widx);
        }
    float b0 = bias[ct0 * 16 + row];
    float b1 = bias[ct0 * 16 + 16 + row];
    float w0 = Wf[ct0 * 16 + row];
    float w1 = Wf[ct0 * 16 + 16 + row];

    for (int t = blockIdx.x; t < NTILE; t += gridDim.x) {
        int n0 = t * 16;
        const unsigned* a0 = A0p + (size_t)(n0 + row) * 128 + kb * 8;
        const unsigned* a1 = A1p + (size_t)(n0 + row) * 128 + kb * 8;
        uint4 aq[16];
#pragma unroll
        for (int kc = 0; kc < 4; ++kc) {
            aq[2 * kc + 0] = *(const uint4*)(a0 + kc * 32);
            aq[2 * kc + 1] = *(const uint4*)(a0 + kc * 32 + 4);
        }
#pragma unroll
        for (int kc = 0; kc < 4; ++kc) {
            aq[8 + 2 * kc + 0] = *(const uint4*)(a1 + kc * 32);
            aq[8 + 2 * kc + 1] = *(const uint4*)(a1 + kc * 32 + 4);
        }
        f32x4 acc0 = {0.f, 0.f, 0.f, 0.f};
        f32x4 acc1 = {0.f, 0.f, 0.f, 0.f};
#pragma unroll
        for (int kc = 0; kc < 8; ++kc) {
            uint4 q0 = aq[2 * kc];
            uint4 q1 = aq[2 * kc + 1];
            unsigned pk[8] = {q0.x, q0.y, q0.z, q0.w, q1.x, q1.y, q1.z, q1.w};
            bf16x8 ah, al;
#pragma unroll
            for (int j = 0; j < 8; ++j) {
                ah[j] = (short)(pk[j] >> 16);
                al[j] = (short)(pk[j] & 0xFFFFu);
            }
            acc0 = __builtin_amdgcn_mfma_f32_16x16x32_bf16(ah, bh[0][kc], acc0, 0, 0, 0);
            acc0 = __builtin_amdgcn_mfma_f32_16x16x32_bf16(al, bh[0][kc], acc0, 0, 0, 0);
            acc0 = __builtin_amdgcn_mfma_f32_16x16x32_bf16(ah, bl[0][kc], acc0, 0, 0, 0);
            acc1 = __builtin_amdgcn_mfma_f32_16x16x32_bf16(ah, bh[1][kc], acc1, 0, 0, 0);
            acc1 = __builtin_amdgcn_mfma_f32_16x16x32_bf16(al, bh[1][kc], acc1, 0, 0, 0);
            acc1 = __builtin_amdgcn_mfma_f32_16x16x32_bf16(ah, bl[1][kc], acc1, 0, 0, 0);
        }
        float part[4];
#pragma unroll
        for (int r = 0; r < 4; ++r)
            part[r] = fmaxf(acc0[r] + b0, 0.f) * w0 + fmaxf(acc1[r] + b1, 0.f) * w1;
#pragma unroll
        for (int o = 1; o < 16; o <<= 1) {
#pragma unroll
            for (int r = 0; r < 4; ++r) part[r] += __shfl_xor(part[r], o);
        }
        if (row == 0) {
#pragma unroll
            for (int r = 0; r < 4; ++r) atomicAdd(&out[n0 + kb * 4 + r], part[r]);
        }
    }
}

extern "C" void kernel_launch(void* const* d_in, const int* in_sizes, int n_in,
                              void* d_out, int out_size, void* d_ws, size_t ws_size,
                              hipStream_t stream) {
    const float* x   = (const float*)d_in[0];
    const int*   ei  = (const int*)d_in[1];
    const float* Wl0 = (const float*)d_in[2];
    const float* bl0 = (const float*)d_in[3];
    const float* Wr0 = (const float*)d_in[4];
    const float* Wl1 = (const float*)d_in[5];
    const float* bl1 = (const float*)d_in[6];
    const float* Wr1 = (const float*)d_in[7];
    const float* Wl2 = (const float*)d_in[8];
    const float* bl2 = (const float*)d_in[9];
    const float* Wr2 = (const float*)d_in[10];
    const float* Wf  = (const float*)d_in[11];
    const float* bf  = (const float*)d_in[12];
    float* out = (float*)d_out;

    char* p = (char*)d_ws;
    auto alloc = [&](size_t n) { void* r = (void*)p; p += (n + 255) & ~(size_t)255; return r; };
    int*            hist      = (int*)alloc((size_t)NBLK * 256 * 4);
    int*            tot       = (int*)alloc(256 * 4);
    int*            dbase     = (int*)alloc(257 * 4);
    int*            cnt       = (int*)alloc((size_t)NN * 4);
    int*            row_start = (int*)alloc((size_t)NN * 4);
    unsigned short* perm      = (unsigned short*)alloc((size_t)NE * 2);
    unsigned*       sbuf      = (unsigned*)alloc((size_t)NN * 128 * 4);
    unsigned*       hp        = (unsigned*)alloc((size_t)NN * 128 * 4);
    unsigned short* whi       = (unsigned short*)alloc((size_t)3 * 128 * 256 * 2);
    unsigned short* wlo       = (unsigned short*)alloc((size_t)3 * 128 * 256 * 2);
    unsigned*       packed    = sbuf;   // alias: consumed before first aggregate

    dim3 b256(256);
    // CSR build via bucket sort
    k_hist<<<dim3(NBLK), b256, 0, stream>>>(ei, hist);
    k_colscan<<<dim3(256), b256, 0, stream>>>(hist, tot);
    k_total<<<dim3(1), b256, 0, stream>>>(tot, dbase);
    k_addbase<<<dim3(NBLK), b256, 0, stream>>>(hist, dbase);
    k_scatter1<<<dim3(NBLK), b256, 0, stream>>>(ei, hist, packed);
    k_bucket_csr<<<dim3(NBUCK), b256, 0, stream>>>(packed, dbase, perm, cnt, row_start);

    // packing + out init
    k_pack_x<<<dim3((NN * 128 / 4 + 255) / 256), b256, 0, stream>>>(x, hp);
    k_pack_w<<<dim3(128), b256, 0, stream>>>(Wl0, Wr0, whi + 0 * 32768, wlo + 0 * 32768);
    k_pack_w<<<dim3(128), b256, 0, stream>>>(Wl1, Wr1, whi + 1 * 32768, wlo + 1 * 32768);
    k_pack_w<<<dim3(128), b256, 0, stream>>>(Wl2, Wr2, whi + 2 * 32768, wlo + 2 * 32768);
    k_init_out<<<dim3((NN + 255) / 256), b256, 0, stream>>>(out, bf);

    dim3 gAgg((NN + 3) / 4);    // 1 node/wave, 4 per block
    dim3 gGemm(512);            // 2 blocks/CU; grid-stride over 3125 tiles

    // layer 0
    k_aggregate<<<gAgg, b256, 0, stream>>>(hp, row_start, cnt, perm, sbuf);
    k_gemm_ws<<<gGemm, b256, 0, stream>>>(sbuf, hp, whi + 0 * 32768, wlo + 0 * 32768, bl0, hp);
    // layer 1 (in place)
    k_aggregate<<<gAgg, b256, 0, stream>>>(hp, row_start, cnt, perm, sbuf);
    k_gemm_ws<<<gGemm, b256, 0, stream>>>(sbuf, hp, whi + 1 * 32768, wlo + 1 * 32768, bl1, hp);
    // layer 2 + fused head
    k_aggregate<<<gAgg, b256, 0, stream>>>(hp, row_start, cnt, perm, sbuf);
    k_gemm_head<<<gGemm, b256, 0, stream>>>(sbuf, hp, whi + 2 * 32768, wlo + 2 * 32768, bl2, Wf, out);
}